// Round 2
// baseline (303.015 us; speedup 1.0000x reference)
//
#include <hip/hip_runtime.h>
#include <hip/hip_bf16.h>

// Problem: B=8, C=256, T=16, H=28, W=28
//   h_t = 0.5*(W @ h_{t-1} + x_t); out[:,:,0]=x0, out[:,:,t]=h_t
//
// R2: latency-bound fix. Per-step chain was ds_read -> MFMA -> global load x
// -> store -> __syncthreads (full vmcnt drain). Now: x_{t+1} prefetched into
// registers during step t, and the barrier is raw `s_waitcnt lgkmcnt(0);
// s_barrier` so global stores/prefetch loads stay in flight across it.

typedef __attribute__((ext_vector_type(8))) short bf16x8;  // 8 bf16 = 4 VGPRs
typedef __attribute__((ext_vector_type(4))) float f32x4;

#define NTILES 49       // 784/16 spatial tiles per batch -> 392 blocks
#define LDSK   264      // 256 + 8 bf16 pad (16B-multiple stride of 528 B)

__device__ __forceinline__ int pkbf2(float a, float b) {
    // two fp32 -> packed bf16x2 (RNE), v_cvt_pk_bf16_f32 on gfx950
    __hip_bfloat162 h = __float22bfloat162_rn(make_float2(a, b));
    union { __hip_bfloat162 h2; int i; } u; u.h2 = h; return u.i;
}

__device__ __forceinline__ short f2bf(float f) {
    union { float f; unsigned u; } v; v.f = f;
    unsigned r = v.u + 0x7FFFu + ((v.u >> 16) & 1u);
    return (short)(r >> 16);
}

__global__ __launch_bounds__(256, 2)
void rcu_kernel(const float* __restrict__ in, const float* __restrict__ Wm,
                float* __restrict__ out) {
    // double-buffered h in bf16, [n=16][k=256+8] layout: 16896 B
    __shared__ short hbuf[2][16][LDSK];

    const int tid  = threadIdx.x;
    const int wave = tid >> 6;      // wave w owns output channels [w*64, w*64+64)
    const int lane = tid & 63;
    const int l15  = lane & 15;     // spatial col within tile / MFMA n
    const int quad = lane >> 4;

    const int b  = blockIdx.x / NTILES;
    const int s0 = (blockIdx.x % NTILES) * 16;

    // ---- W as bf16 A-fragments in registers (loaded once, reused 15 steps) ----
    // A[m][k]: m = 16-tile base + (lane&15), k = quad*8 + j
    bf16x8 a_frag[4][8];            // 128 VGPRs
#pragma unroll
    for (int mt = 0; mt < 4; ++mt) {
        const int m = wave * 64 + mt * 16 + l15;
        const float* wrow = Wm + m * 256 + quad * 8;
#pragma unroll
        for (int ks = 0; ks < 8; ++ks) {
            float4 f0 = *(const float4*)(wrow + ks * 32);
            float4 f1 = *(const float4*)(wrow + ks * 32 + 4);
            bf16x8 a;
            a[0] = f2bf(f0.x); a[1] = f2bf(f0.y); a[2] = f2bf(f0.z); a[3] = f2bf(f0.w);
            a[4] = f2bf(f1.x); a[5] = f2bf(f1.y); a[6] = f2bf(f1.z); a[7] = f2bf(f1.w);
            a_frag[mt][ks] = a;
        }
    }

    // Flat index: ((b*256 + c)*16 + t)*784 + s
    const size_t base = (size_t)b * 256 * 16 * 784 + s0;
    const float* xin  = in  + base;
    float*       xout = out + base;

    // ---- init t=0 in D-fragment layout: h0 = x0, copy through, stage LDS ----
    float px[16];                    // prefetched x for the step being computed
#pragma unroll
    for (int mt = 0; mt < 4; ++mt) {
        const int c0 = wave * 64 + mt * 16 + quad * 4;
        float v[4];
#pragma unroll
        for (int r = 0; r < 4; ++r) {
            const size_t off = (size_t)(c0 + r) * 16 * 784 + l15;   // t=0
            v[r] = xin[off];
            xout[off] = v[r];
        }
        int2 packed;
        packed.x = pkbf2(v[0], v[1]);
        packed.y = pkbf2(v[2], v[3]);
        *(int2*)&hbuf[0][l15][c0] = packed;          // 8B aligned (528-B rows)
#pragma unroll
        for (int r = 0; r < 4; ++r)                   // prefetch x_{t=1}
            px[mt * 4 + r] = xin[((size_t)(c0 + r) * 16 + 1) * 784 + l15];
    }
    __syncthreads();    // one full barrier at init is fine

    int cur = 0;
#pragma unroll
    for (int t = 1; t < 16; ++t) {
        // B fragments: B[k][n], k = ks*32 + quad*8 + j, n = lane&15
        bf16x8 bfrag[8];
        const short* hp = &hbuf[cur][l15][quad * 8];
#pragma unroll
        for (int ks = 0; ks < 8; ++ks)
            bfrag[ks] = *(const bf16x8*)(hp + ks * 32);   // ds_read_b128

        // issue next step's x loads now; latency hides under MFMA + stores
        float pxn[16];
        if (t < 15) {
#pragma unroll
            for (int mt = 0; mt < 4; ++mt) {
                const int c0 = wave * 64 + mt * 16 + quad * 4;
#pragma unroll
                for (int r = 0; r < 4; ++r)
                    pxn[mt * 4 + r] = xin[((size_t)(c0 + r) * 16 + (t + 1)) * 784 + l15];
            }
        }

        const int nxt = cur ^ 1;
#pragma unroll
        for (int mt = 0; mt < 4; ++mt) {
            f32x4 acc = {0.f, 0.f, 0.f, 0.f};
#pragma unroll
            for (int ks = 0; ks < 8; ++ks)
                acc = __builtin_amdgcn_mfma_f32_16x16x32_bf16(a_frag[mt][ks], bfrag[ks], acc, 0, 0, 0);

            // D layout: channel = c0 + r (r = acc reg), col = lane&15
            const int c0 = wave * 64 + mt * 16 + quad * 4;
            float v[4];
#pragma unroll
            for (int r = 0; r < 4; ++r) {
                v[r] = 0.5f * (acc[r] + px[mt * 4 + r]);
                xout[((size_t)(c0 + r) * 16 + t) * 784 + l15] = v[r];
            }
            int2 packed;
            packed.x = pkbf2(v[0], v[1]);
            packed.y = pkbf2(v[2], v[3]);
            *(int2*)&hbuf[nxt][l15][c0] = packed;
        }

        // LDS-only barrier: wait our wave's LDS reads+writes, then s_barrier.
        // Global stores & prefetch loads stay in flight (no vmcnt drain).
        __asm__ volatile("s_waitcnt lgkmcnt(0)\n\ts_barrier" ::: "memory");

#pragma unroll
        for (int i = 0; i < 16; ++i) px[i] = pxn[i];
        cur = nxt;
    }
}

extern "C" void kernel_launch(void* const* d_in, const int* in_sizes, int n_in,
                              void* d_out, int out_size, void* d_ws, size_t ws_size,
                              hipStream_t stream) {
    const float* in  = (const float*)d_in[0];
    const float* Wm  = (const float*)d_in[1];
    float*       out = (float*)d_out;
    hipLaunchKernelGGL(rcu_kernel, dim3(8 * NTILES), dim3(256), 0, stream, in, Wm, out);
}

// Round 3
// 231.975 us; speedup vs baseline: 1.3062x; 1.3062x over previous
//
#include <hip/hip_runtime.h>
#include <hip/hip_bf16.h>

// Problem: B=8, C=256, T=16, H=28, W=28
//   h_t = 0.5*(W @ h_{t-1} + x_t); out[:,:,0]=x0, out[:,:,t]=h_t
//
// R3: R1 was Little's-law starved (~6KB/CU in flight -> 2.1 TB/s). R2's
// register prefetch spilled (R1 sat exactly at the 256-reg (256,2) cap).
// Fix: x_t staged via global_load_lds (zero VGPR cost) issued at step top,
// consumed at epilogue after `s_waitcnt vmcnt(0)`; h handoff keeps the
// validated lgkm-only barrier so stores stay in flight across steps.

typedef __attribute__((ext_vector_type(8))) short bf16x8;  // 8 bf16 = 4 VGPRs
typedef __attribute__((ext_vector_type(4))) float f32x4;

#define NTILES 49       // 784/16 spatial tiles per batch -> 392 blocks
#define LDSK   264      // h stride: 528 B = 33 x 16B -> b128 reads conflict-free
#define CSTRIDE 12544   // 16*784: elements between channels

#define AS1 __attribute__((address_space(1)))
#define AS3 __attribute__((address_space(3)))

__device__ __forceinline__ void ld_lds16(const float* g, float* l) {
    // async 16B/lane global -> LDS; LDS dst = wave-uniform base + lane*16
    __builtin_amdgcn_global_load_lds((AS1 const unsigned int*)g,
                                     (AS3 unsigned int*)l, 16, 0, 0);
}

__device__ __forceinline__ int pkbf2(float a, float b) {
    __hip_bfloat162 h = __float22bfloat162_rn(make_float2(a, b));
    union { __hip_bfloat162 h2; int i; } u; u.h2 = h; return u.i;
}

__device__ __forceinline__ short f2bf(float f) {
    union { float f; unsigned u; } v; v.f = f;
    unsigned r = v.u + 0x7FFFu + ((v.u >> 16) & 1u);
    return (short)(r >> 16);
}

__global__ __launch_bounds__(256, 2)
void rcu_kernel(const float* __restrict__ in, const float* __restrict__ Wm,
                float* __restrict__ out) {
    __shared__ short hbuf[2][16][LDSK];   // h as bf16, [n=16][k=256+8]: 16.9 KB
    __shared__ float xslab[256 * 16];     // x_t staging, [ch][col] fp32: 16 KB

    const int tid  = threadIdx.x;
    const int wave = tid >> 6;      // wave w owns output channels [w*64, w*64+64)
    const int lane = tid & 63;
    const int l15  = lane & 15;     // spatial col / MFMA n
    const int quad = lane >> 4;

    const int b  = blockIdx.x / NTILES;
    const int s0 = (blockIdx.x % NTILES) * 16;

    // Flat index: ((b*256 + c)*16 + t)*784 + s
    const size_t base = (size_t)b * 256 * CSTRIDE + s0;
    const float* xin  = in  + base;
    float*       xout = out + base;

    // per-lane mapping for global_load_lds: lane L covers channel cb+L/4,
    // cols (L&3)*4 .. +3 (16B contiguous in global)
    const int pf_c   = lane >> 2;         // channel within 16-ch group
    const int pf_col = (lane & 3) * 4;

    // ---- issue x0 prefetch first (overlaps W load latency) ----
#pragma unroll
    for (int i = 0; i < 4; ++i) {
        const int cb = wave * 64 + i * 16;
        ld_lds16(xin + (size_t)(cb + pf_c) * CSTRIDE + pf_col,
                 &xslab[cb * 16]);
    }

    // ---- W as bf16 A-fragments in registers (reused all 15 steps) ----
    bf16x8 a_frag[4][8];            // 128 regs
#pragma unroll
    for (int mt = 0; mt < 4; ++mt) {
        const int m = wave * 64 + mt * 16 + l15;
        const float* wrow = Wm + m * 256 + quad * 8;
#pragma unroll
        for (int ks = 0; ks < 8; ++ks) {
            float4 f0 = *(const float4*)(wrow + ks * 32);
            float4 f1 = *(const float4*)(wrow + ks * 32 + 4);
            bf16x8 a;
            a[0] = f2bf(f0.x); a[1] = f2bf(f0.y); a[2] = f2bf(f0.z); a[3] = f2bf(f0.w);
            a[4] = f2bf(f1.x); a[5] = f2bf(f1.y); a[6] = f2bf(f1.z); a[7] = f2bf(f1.w);
            a_frag[mt][ks] = a;
        }
    }

    // ---- init t=0: h0 = x0 from slab; copy to out; stage hbuf[0] ----
    __asm__ volatile("s_waitcnt vmcnt(0)" ::: "memory");  // x0 slab ready
#pragma unroll
    for (int mt = 0; mt < 4; ++mt) {
        const int c0 = wave * 64 + mt * 16 + quad * 4;
        float v[4];
#pragma unroll
        for (int r = 0; r < 4; ++r) {
            v[r] = xslab[(c0 + r) * 16 + l15];
            xout[(size_t)(c0 + r) * CSTRIDE + l15] = v[r];
        }
        int2 packed;
        packed.x = pkbf2(v[0], v[1]);
        packed.y = pkbf2(v[2], v[3]);
        *(int2*)&hbuf[0][l15][c0] = packed;
    }
    __asm__ volatile("s_waitcnt lgkmcnt(0)\n\ts_barrier" ::: "memory");

    int cur = 0;
    int tof = 784;                   // t*784
#pragma unroll 1
    for (int t = 1; t < 16; ++t) {
        // 1) issue this step's x_t staging (consumed ~600 cyc later)
#pragma unroll
        for (int i = 0; i < 4; ++i) {
            const int cb = wave * 64 + i * 16;
            ld_lds16(xin + (size_t)(cb + pf_c) * CSTRIDE + tof + pf_col,
                     &xslab[cb * 16]);
        }

        // 2) h_{t-1} B-fragments: B[k][n], k = ks*32 + quad*8 + j, n = l15
        bf16x8 bfrag[8];
        const short* hp = &hbuf[cur][l15][quad * 8];
#pragma unroll
        for (int ks = 0; ks < 8; ++ks)
            bfrag[ks] = *(const bf16x8*)(hp + ks * 32);   // ds_read_b128

        // 3) W @ h
        f32x4 acc[4];
#pragma unroll
        for (int mt = 0; mt < 4; ++mt) {
            f32x4 a0 = {0.f, 0.f, 0.f, 0.f};
#pragma unroll
            for (int ks = 0; ks < 8; ++ks)
                a0 = __builtin_amdgcn_mfma_f32_16x16x32_bf16(a_frag[mt][ks], bfrag[ks], a0, 0, 0, 0);
            acc[mt] = a0;
        }

        // 4) wait x_t slab (P(t) issued at top; old stores long done)
        __asm__ volatile("s_waitcnt vmcnt(0)" ::: "memory");

        // 5) epilogue: v = 0.5*(Wh + x); store out; stage h_t into hbuf
        const int nxt = cur ^ 1;
#pragma unroll
        for (int mt = 0; mt < 4; ++mt) {
            const int c0 = wave * 64 + mt * 16 + quad * 4;
            float v[4];
#pragma unroll
            for (int r = 0; r < 4; ++r) {
                v[r] = 0.5f * (acc[mt][r] + xslab[(c0 + r) * 16 + l15]);
                xout[(size_t)(c0 + r) * CSTRIDE + tof + l15] = v[r];
            }
            int2 packed;
            packed.x = pkbf2(v[0], v[1]);
            packed.y = pkbf2(v[2], v[3]);
            *(int2*)&hbuf[nxt][l15][c0] = packed;
        }

        // 6) h handoff barrier: LDS-only drain; stores stay in flight
        __asm__ volatile("s_waitcnt lgkmcnt(0)\n\ts_barrier" ::: "memory");

        tof += 784;
        cur = nxt;
    }
}

extern "C" void kernel_launch(void* const* d_in, const int* in_sizes, int n_in,
                              void* d_out, int out_size, void* d_ws, size_t ws_size,
                              hipStream_t stream) {
    const float* in  = (const float*)d_in[0];
    const float* Wm  = (const float*)d_in[1];
    float*       out = (float*)d_out;
    hipLaunchKernelGGL(rcu_kernel, dim3(8 * NTILES), dim3(256), 0, stream, in, Wm, out);
}